// Round 4
// baseline (655.835 us; speedup 1.0000x reference)
//
#include <hip/hip_runtime.h>
#include <math.h>

typedef short bf16x8 __attribute__((ext_vector_type(8)));
typedef float f32x4 __attribute__((ext_vector_type(4)));
typedef unsigned short u16;

// ---------------------------------------------------------------- helpers
__device__ __forceinline__ u16 f2bf(float f) {
    union { float f; unsigned u; } v; v.f = f;
    unsigned r = v.u + 0x7fffu + ((v.u >> 16) & 1u);
    return (u16)(r >> 16);
}

__device__ __forceinline__ void gload_lds16(const void* g, void* l) {
    __builtin_amdgcn_global_load_lds((const __attribute__((address_space(1))) void*)g,
                                     (__attribute__((address_space(3))) void*)l, 16, 0, 0);
}

// ---------------------------------------------------------------- transpose+cvt
__global__ __launch_bounds__(256)
void transpose_cvt(const float* __restrict__ in, u16* __restrict__ out, int R, int C)
{
    __shared__ float tile[64][65];
    const size_t slab = (size_t)blockIdx.z * R * C;
    const float* ip = in + slab;
    u16* op = out + slab;
    const int r0 = blockIdx.y * 64, c0 = blockIdx.x * 64;
    const int t = threadIdx.x;
    const int tr = t >> 6, tc = t & 63;
    #pragma unroll
    for (int i = 0; i < 16; ++i)
        tile[tr + i*4][tc] = ip[(size_t)(r0 + tr + i*4)*C + c0 + tc];
    __syncthreads();
    #pragma unroll
    for (int i = 0; i < 16; ++i)
        op[(size_t)(c0 + tr + i*4)*R + r0 + tc] = f2bf(tile[tc][tr + i*4]);
}

// ---------------------------------------------------------------- layernorm
__global__ __launch_bounds__(256)
void ln_kernel(const float* __restrict__ x, const float* __restrict__ g,
               const float* __restrict__ b, u16* __restrict__ out)
{
    const int row = blockIdx.x;
    const int t = threadIdx.x;
    const float4 v = ((const float4*)(x + (size_t)row*1024))[t];
    float s = v.x + v.y + v.z + v.w;
    float ss = v.x*v.x + v.y*v.y + v.z*v.z + v.w*v.w;
    #pragma unroll
    for (int m = 1; m < 64; m <<= 1) {
        s  += __shfl_xor(s, m);
        ss += __shfl_xor(ss, m);
    }
    __shared__ float red[8];
    const int wave = t >> 6;
    if ((t & 63) == 0) { red[wave] = s; red[4 + wave] = ss; }
    __syncthreads();
    s  = red[0] + red[1] + red[2] + red[3];
    ss = red[4] + red[5] + red[6] + red[7];
    const float mu = s * (1.f/1024.f);
    const float rs = rsqrtf(ss * (1.f/1024.f) - mu*mu + 1e-5f);
    const float4 gv = ((const float4*)g)[t];
    const float4 bv = ((const float4*)b)[t];
    ushort4 ov;
    ov.x = f2bf((v.x - mu)*rs*gv.x + bv.x);
    ov.y = f2bf((v.y - mu)*rs*gv.y + bv.y);
    ov.z = f2bf((v.z - mu)*rs*gv.z + bv.z);
    ov.w = f2bf((v.w - mu)*rs*gv.w + bv.w);
    ((ushort4*)(out + (size_t)row*1024))[t] = ov;
}

// ---------------------------------------------------------------- GEMM 256xBN, BK=64, 4-phase schedule
// A [8192][K] bf16 row-major, BT [N][K] bf16 row-major. M-tiles fixed: 32.
// 512 threads = 8 waves (2 M x 4 N). Per-wave out: 128 x BN/4.
// EPI 0: QKV split; EPI 1: f32 acc+bias+res; EPI 2: bf16 relu(acc+bias).
template<int NWG, int BN, int N, int K, int EPI>
__global__ __launch_bounds__(512, 2)
void gemm256_kernel(const u16* __restrict__ A, const u16* __restrict__ BT,
                    float* __restrict__ out_f32, u16* __restrict__ out_bf16,
                    const float* __restrict__ bias, const float* __restrict__ res,
                    u16* __restrict__ qbuf, u16* __restrict__ kbuf, u16* __restrict__ vt)
{
    constexpr int NI  = BN / 128;      // B-frags per quadrant (2 for BN=256, 1 for BN=128)
    constexpr int WC  = BN / 4;        // wave cols
    constexpr int SIB = BN / 64;       // B staging issues
    __shared__ u16 As[2][256*64];
    __shared__ u16 Bs[2][BN*64];

    const int bid = blockIdx.x;
    const int tid = ((bid & 7) * (NWG / 8)) + (bid >> 3);   // bijective XCD swizzle
    const int m0 = (tid & 31) * 256;
    const int n0 = (tid >> 5) * BN;
    const int t = threadIdx.x;
    const int lane = t & 63;
    const int l15 = lane & 15, lg = lane >> 4;
    const int wid = t >> 6;
    const int wm = wid >> 2, wn = wid & 3;
    const int swzf = (l15 & 7) << 4;   // read swizzle (bytes)

    f32x4 acc[2][2][4][NI] = {};
    bf16x8 af[4][2], b0[NI][2], b1[NI][2];

    // staging: thread t stages 16B; chunk i = 64 rows; dest linear = i*8KB + t*16B
    const int srow = t >> 3;                     // row within chunk
    const int sg8  = ((t & 7) ^ (srow & 7)) * 8; // pre-swizzled src col (u16 units)

    #define STAGE_G(BUF, K0) do { \
        _Pragma("unroll") \
        for (int i = 0; i < 4; ++i) \
            gload_lds16(A + (size_t)(m0 + i*64 + srow)*K + (K0) + sg8, &As[BUF][i*4096 + t*8]); \
        _Pragma("unroll") \
        for (int i = 0; i < SIB; ++i) \
            gload_lds16(BT + (size_t)(n0 + i*64 + srow)*K + (K0) + sg8, &Bs[BUF][i*4096 + t*8]); \
    } while (0)

    #define RD_A(QM) do { \
        _Pragma("unroll") \
        for (int mi = 0; mi < 4; ++mi) \
            _Pragma("unroll") \
            for (int kk = 0; kk < 2; ++kk) \
                af[mi][kk] = *(const bf16x8*)((const char*)&As[cur][0] \
                    + (wm*128 + (QM)*64 + mi*16 + l15)*128 + ((kk*64 + lg*16) ^ swzf)); \
    } while (0)

    #define RD_B(QN, DST) do { \
        _Pragma("unroll") \
        for (int ni = 0; ni < NI; ++ni) \
            _Pragma("unroll") \
            for (int kk = 0; kk < 2; ++kk) \
                DST[ni][kk] = *(const bf16x8*)((const char*)&Bs[cur][0] \
                    + (wn*WC + (QN)*(WC/2) + ni*16 + l15)*128 + ((kk*64 + lg*16) ^ swzf)); \
    } while (0)

    #define MFMAQ(QM, QN, BF) do { \
        _Pragma("unroll") \
        for (int mi = 0; mi < 4; ++mi) \
            _Pragma("unroll") \
            for (int ni = 0; ni < NI; ++ni) \
                _Pragma("unroll") \
                for (int kk = 0; kk < 2; ++kk) \
                    acc[QM][QN][mi][ni] = __builtin_amdgcn_mfma_f32_16x16x32_bf16( \
                        af[mi][kk], BF[ni][kk], acc[QM][QN][mi][ni], 0, 0, 0); \
    } while (0)

    #define PHASE_PRE()  do { __builtin_amdgcn_sched_barrier(0); __builtin_amdgcn_s_barrier(); \
        asm volatile("s_waitcnt lgkmcnt(0)" ::: "memory"); __builtin_amdgcn_sched_barrier(0); \
        __builtin_amdgcn_s_setprio(1); } while (0)
    #define PHASE_POST() do { __builtin_amdgcn_s_setprio(0); __builtin_amdgcn_sched_barrier(0); \
        __builtin_amdgcn_s_barrier(); } while (0)

    STAGE_G(0, 0);
    asm volatile("s_waitcnt vmcnt(0)" ::: "memory");
    __builtin_amdgcn_s_barrier();

    const int NKT = K / 64;
    for (int kt = 0; kt < NKT; ++kt) {
        const int cur = kt & 1;
        // ---- P0: quadrant (0,0)
        RD_A(0); RD_B(0, b0);
        if (kt + 1 < NKT) STAGE_G(cur ^ 1, (kt + 1) * 64);
        PHASE_PRE();  MFMAQ(0, 0, b0);  PHASE_POST();
        // ---- P1: quadrant (0,1)
        RD_B(1, b1);
        PHASE_PRE();  MFMAQ(0, 1, b1);  PHASE_POST();
        // ---- P2: quadrant (1,1)
        RD_A(1);
        PHASE_PRE();  MFMAQ(1, 1, b1);  PHASE_POST();
        // ---- P3: quadrant (1,0) — drain staging for next iter
        asm volatile("s_waitcnt vmcnt(0)" ::: "memory");
        __builtin_amdgcn_s_barrier();
        __builtin_amdgcn_s_setprio(1);
        MFMAQ(1, 0, b0);
        PHASE_POST();
    }
    #undef STAGE_G
    #undef RD_A
    #undef RD_B
    #undef MFMAQ
    #undef PHASE_PRE
    #undef PHASE_POST

    // ---- epilogue
    #pragma unroll
    for (int qm = 0; qm < 2; ++qm)
      #pragma unroll
      for (int qn = 0; qn < 2; ++qn)
        #pragma unroll
        for (int mi = 0; mi < 4; ++mi)
          #pragma unroll
          for (int ni = 0; ni < NI; ++ni) {
            const int gc = n0 + wn*WC + qn*(WC/2) + ni*16 + l15;
            #pragma unroll
            for (int j = 0; j < 4; ++j) {
                const int gr = m0 + wm*128 + qm*64 + mi*16 + lg*4 + j;
                float v = acc[qm][qn][mi][ni][j];
                if constexpr (EPI == 0) {
                    u16 bv = f2bf(v);
                    if (gc < 1024) {
                        qbuf[(size_t)gr*1024 + gc] = bv;
                    } else if (gc < 2048) {
                        kbuf[(size_t)gr*1024 + (gc - 1024)] = bv;
                    } else {
                        const int hd = gc - 2048;
                        const int bb = gr >> 11, tt = gr & 2047;
                        vt[(size_t)((bb*16 + (hd >> 6))*64 + (hd & 63))*2048 + tt] = bv;
                    }
                } else if constexpr (EPI == 1) {
                    out_f32[(size_t)gr*N + gc] = v + bias[gc] + res[(size_t)gr*N + gc];
                } else {
                    out_bf16[(size_t)gr*N + gc] = f2bf(fmaxf(v + bias[gc], 0.f));
                }
            }
          }
}

// ---------------------------------------------------------------- flash attention v3 (unchanged)
__device__ __forceinline__ void attn_qtile(
    bf16x8 (&qf)[2][2], f32x4 (&o)[2][4], float (&mprev)[2][4], float (&lsum)[2][4],
    const u16* Ksc, const u16* Vsc, u16* pl,
    int key0, int q0, int l15, int lg, int swzf, int swzp)
{
    #pragma unroll
    for (int mi = 0; mi < 2; ++mi) {
        if (key0 > q0 + mi*16 + 15) continue;
        f32x4 s[4] = {};
        #pragma unroll
        for (int n = 0; n < 4; ++n)
            #pragma unroll
            for (int kk = 0; kk < 2; ++kk) {
                const int row = n*16 + l15;
                bf16x8 kf = *(const bf16x8*)((const char*)Ksc
                                + row*128 + ((kk*64 + lg*16) ^ swzf));
                s[n] = __builtin_amdgcn_mfma_f32_16x16x32_bf16(qf[mi][kk], kf, s[n], 0, 0, 0);
            }
        const bool domask = (key0 + 63) > (q0 + mi*16);
        float tm[4] = {-INFINITY, -INFINITY, -INFINITY, -INFINITY};
        #pragma unroll
        for (int n = 0; n < 4; ++n)
            #pragma unroll
            for (int j = 0; j < 4; ++j) {
                float sv = s[n][j] * 0.03125f;
                if (domask && (key0 + n*16 + l15 > q0 + mi*16 + lg*4 + j)) sv = -INFINITY;
                s[n][j] = sv;
                tm[j] = fmaxf(tm[j], sv);
            }
        #pragma unroll
        for (int m = 1; m < 16; m <<= 1)
            #pragma unroll
            for (int j = 0; j < 4; ++j)
                tm[j] = fmaxf(tm[j], __shfl_xor(tm[j], m, 16));
        float alpha[4], rsum[4];
        #pragma unroll
        for (int j = 0; j < 4; ++j) {
            float mn = fmaxf(mprev[mi][j], tm[j]);
            alpha[j] = __expf(mprev[mi][j] - mn);
            mprev[mi][j] = mn;
            rsum[j] = 0.f;
        }
        #pragma unroll
        for (int n = 0; n < 4; ++n)
            #pragma unroll
            for (int j = 0; j < 4; ++j) {
                float pv = __expf(s[n][j] - mprev[mi][j]);
                rsum[j] += pv;
                const int qq = lg*4 + j;
                pl[qq*64 + ((n*16 + l15) ^ ((qq & 7) * 8))] = f2bf(pv);
            }
        #pragma unroll
        for (int m = 1; m < 16; m <<= 1)
            #pragma unroll
            for (int j = 0; j < 4; ++j)
                rsum[j] += __shfl_xor(rsum[j], m, 16);
        #pragma unroll
        for (int j = 0; j < 4; ++j)
            lsum[mi][j] = lsum[mi][j]*alpha[j] + rsum[j];
        #pragma unroll
        for (int dn = 0; dn < 4; ++dn)
            #pragma unroll
            for (int j = 0; j < 4; ++j)
                o[mi][dn][j] *= alpha[j];
        bf16x8 pf[2];
        #pragma unroll
        for (int kk = 0; kk < 2; ++kk)
            pf[kk] = *(const bf16x8*)(pl + l15*64 + ((kk*32 + lg*8) ^ swzp));
        #pragma unroll
        for (int dn = 0; dn < 4; ++dn)
            #pragma unroll
            for (int kk = 0; kk < 2; ++kk) {
                const int row = dn*16 + l15;
                bf16x8 vf = *(const bf16x8*)((const char*)Vsc
                                + row*128 + ((kk*64 + lg*16) ^ swzf));
                o[mi][dn] = __builtin_amdgcn_mfma_f32_16x16x32_bf16(pf[kk], vf, o[mi][dn], 0, 0, 0);
            }
    }
}

__global__ __launch_bounds__(256, 2)
void attn_kernel(const u16* __restrict__ q, const u16* __restrict__ k,
                 const u16* __restrict__ vt, u16* __restrict__ out)
{
    __shared__ u16 Ks[2][4096];
    __shared__ u16 Vs[2][4096];
    __shared__ u16 Plds[4][1024];

    const int bh = blockIdx.x & 63;
    const int pair = blockIdx.x >> 6;
    const int b = bh >> 4, h = bh & 15;
    const int wave = threadIdx.x >> 6, lane = threadIdx.x & 63;
    const int l15 = lane & 15, lg = lane >> 4;
    const int qA = pair, qB = 15 - pair;
    const int q0A = qA*128 + wave*32;
    const int q0B = qB*128 + wave*32;
    const u16* Qp = q + (size_t)b*2048*1024 + h*64;
    const u16* Kp = k + (size_t)b*2048*1024 + h*64;
    const u16* Vp = vt + (size_t)bh*64*2048;
    u16* pl = Plds[wave];

    bf16x8 qfA[2][2], qfB[2][2];
    #pragma unroll
    for (int mi = 0; mi < 2; ++mi)
        #pragma unroll
        for (int kk = 0; kk < 2; ++kk) {
            qfA[mi][kk] = *(const bf16x8*)(Qp + (size_t)(q0A + mi*16 + l15)*1024 + kk*32 + lg*8);
            qfB[mi][kk] = *(const bf16x8*)(Qp + (size_t)(q0B + mi*16 + l15)*1024 + kk*32 + lg*8);
        }

    const int srow0 = wave*8 + (lane >> 3);
    const int scol  = ((lane & 7) ^ (srow0 & 7)) << 3;
    const int swzf  = (l15 & 7) << 4;
    const int swzp  = (l15 & 7) << 3;

    f32x4 oA[2][4] = {}, oB[2][4] = {};
    float mprevA[2][4], lsumA[2][4], mprevB[2][4], lsumB[2][4];
    #pragma unroll
    for (int mi = 0; mi < 2; ++mi)
        #pragma unroll
        for (int j = 0; j < 4; ++j) {
            mprevA[mi][j] = -INFINITY; lsumA[mi][j] = 0.f;
            mprevB[mi][j] = -INFINITY; lsumB[mi][j] = 0.f;
        }

    const int nkt = 32 - 2*pair;

    #define STAGE(buf, key0_) do { \
        gload_lds16(Kp + (size_t)((key0_) + srow0)*1024 + scol,      &Ks[buf][wave*512]); \
        gload_lds16(Kp + (size_t)((key0_) + srow0 + 32)*1024 + scol, &Ks[buf][(4+wave)*512]); \
        gload_lds16(Vp + (size_t)srow0*2048 + (key0_) + scol,        &Vs[buf][wave*512]); \
        gload_lds16(Vp + (size_t)(srow0+32)*2048 + (key0_) + scol,   &Vs[buf][(4+wave)*512]); \
    } while (0)

    STAGE(0, 0);

    for (int kt = 0; kt < nkt; ++kt) {
        const int cur = kt & 1;
        const int key0 = kt * 64;
        if (kt + 1 < nkt) {
            STAGE(cur ^ 1, key0 + 64);
            asm volatile("s_waitcnt vmcnt(4)" ::: "memory");
        } else {
            asm volatile("s_waitcnt vmcnt(0)" ::: "memory");
        }
        __builtin_amdgcn_s_barrier();
        __builtin_amdgcn_sched_barrier(0);

        if (key0 <= q0A + 31)
            attn_qtile(qfA, oA, mprevA, lsumA, &Ks[cur][0], &Vs[cur][0], pl,
                       key0, q0A, l15, lg, swzf, swzp);
        if (key0 <= q0B + 31)
            attn_qtile(qfB, oB, mprevB, lsumB, &Ks[cur][0], &Vs[cur][0], pl,
                       key0, q0B, l15, lg, swzf, swzp);

        __builtin_amdgcn_sched_barrier(0);
        __builtin_amdgcn_s_barrier();
    }
    #undef STAGE

    #pragma unroll
    for (int mi = 0; mi < 2; ++mi)
        #pragma unroll
        for (int dn = 0; dn < 4; ++dn)
            #pragma unroll
            for (int j = 0; j < 4; ++j) {
                float vA = oA[mi][dn][j] / lsumA[mi][j];
                out[(size_t)(b*2048 + q0A + mi*16 + lg*4 + j)*1024 + h*64 + dn*16 + l15] = f2bf(vA);
                float vB = oB[mi][dn][j] / lsumB[mi][j];
                out[(size_t)(b*2048 + q0B + mi*16 + lg*4 + j)*1024 + h*64 + dn*16 + l15] = f2bf(vB);
            }
}

// ---------------------------------------------------------------- launch
#define MB(x) ((size_t)(x) << 20)

extern "C" void kernel_launch(void* const* d_in, const int* in_sizes, int n_in,
                              void* d_out, int out_size, void* d_ws, size_t ws_size,
                              hipStream_t stream) {
    const float* x      = (const float*)d_in[0];
    const float* Wq     = (const float*)d_in[1];
    const float* Wk     = (const float*)d_in[2];
    const float* Wv     = (const float*)d_in[3];
    const float* Wproj  = (const float*)d_in[4];
    const float* bproj  = (const float*)d_in[5];
    const float* ln1_g  = (const float*)d_in[6];
    const float* ln1_b  = (const float*)d_in[7];
    const float* ln2_g  = (const float*)d_in[8];
    const float* ln2_b  = (const float*)d_in[9];
    const float* W1     = (const float*)d_in[10];
    const float* b1     = (const float*)d_in[11];
    const float* W2     = (const float*)d_in[12];
    const float* b2     = (const float*)d_in[13];
    float* out = (float*)d_out;

    char* ws = (char*)d_ws;
    u16*  h      = (u16*)(ws + MB(0));
    u16*  qbuf   = (u16*)(ws + MB(16));
    u16*  kbuf   = (u16*)(ws + MB(32));
    u16*  vt     = (u16*)(ws + MB(48));
    u16*  attn   = (u16*)(ws + MB(64));
    float* x2    = (float*)(ws + MB(80));
    u16*  BTqkv  = (u16*)(ws + MB(112));
    u16*  BTproj = (u16*)(ws + MB(118));
    u16*  BT1    = (u16*)(ws + MB(120));
    u16*  BT2    = (u16*)(ws + MB(128));
    u16*  ff     = (u16*)(ws + MB(16));
    u16*  h2     = h;

    transpose_cvt<<<dim3(1,16,16),  256, 0, stream>>>(Wq,    BTqkv,             1024, 64);
    transpose_cvt<<<dim3(1,16,16),  256, 0, stream>>>(Wk,    BTqkv + (1<<20),   1024, 64);
    transpose_cvt<<<dim3(1,16,16),  256, 0, stream>>>(Wv,    BTqkv + (2<<20),   1024, 64);
    transpose_cvt<<<dim3(16,16,1),  256, 0, stream>>>(Wproj, BTproj,            1024, 1024);
    transpose_cvt<<<dim3(64,16,1),  256, 0, stream>>>(W1,    BT1,               1024, 4096);
    transpose_cvt<<<dim3(16,64,1),  256, 0, stream>>>(W2,    BT2,               4096, 1024);

    ln_kernel<<<8192, 256, 0, stream>>>(x, ln1_g, ln1_b, h);
    gemm256_kernel<384,256,3072,1024,0><<<384, 512, 0, stream>>>(h, BTqkv, nullptr, nullptr,
        nullptr, nullptr, qbuf, kbuf, vt);
    attn_kernel<<<512, 256, 0, stream>>>(qbuf, kbuf, vt, attn);
    gemm256_kernel<256,128,1024,1024,1><<<256, 512, 0, stream>>>(attn, BTproj, x2, nullptr,
        bproj, x, nullptr, nullptr, nullptr);
    ln_kernel<<<8192, 256, 0, stream>>>(x2, ln2_g, ln2_b, h2);
    gemm256_kernel<512,256,4096,1024,2><<<512, 512, 0, stream>>>(h2, BT1, nullptr, ff,
        b1, nullptr, nullptr, nullptr, nullptr);
    gemm256_kernel<256,128,1024,4096,1><<<256, 512, 0, stream>>>(ff, BT2, out, nullptr,
        b2, x2, nullptr, nullptr, nullptr);
}

// Round 5
// 603.538 us; speedup vs baseline: 1.0867x; 1.0867x over previous
//
#include <hip/hip_runtime.h>
#include <math.h>

typedef short bf16x8 __attribute__((ext_vector_type(8)));
typedef float f32x4 __attribute__((ext_vector_type(4)));
typedef unsigned short u16;

// ---------------------------------------------------------------- helpers
__device__ __forceinline__ u16 f2bf(float f) {
    union { float f; unsigned u; } v; v.f = f;
    unsigned r = v.u + 0x7fffu + ((v.u >> 16) & 1u);
    return (u16)(r >> 16);
}

__device__ __forceinline__ void gload_lds16(const void* g, void* l) {
    __builtin_amdgcn_global_load_lds((const __attribute__((address_space(1))) void*)g,
                                     (__attribute__((address_space(3))) void*)l, 16, 0, 0);
}

// ---------------------------------------------------------------- transpose+cvt
__global__ __launch_bounds__(256)
void transpose_cvt(const float* __restrict__ in, u16* __restrict__ out, int R, int C)
{
    __shared__ float tile[64][65];
    const size_t slab = (size_t)blockIdx.z * R * C;
    const float* ip = in + slab;
    u16* op = out + slab;
    const int r0 = blockIdx.y * 64, c0 = blockIdx.x * 64;
    const int t = threadIdx.x;
    const int tr = t >> 6, tc = t & 63;
    #pragma unroll
    for (int i = 0; i < 16; ++i)
        tile[tr + i*4][tc] = ip[(size_t)(r0 + tr + i*4)*C + c0 + tc];
    __syncthreads();
    #pragma unroll
    for (int i = 0; i < 16; ++i)
        op[(size_t)(c0 + tr + i*4)*R + r0 + tc] = f2bf(tile[tc][tr + i*4]);
}

// ---------------------------------------------------------------- layernorm
__global__ __launch_bounds__(256)
void ln_kernel(const float* __restrict__ x, const float* __restrict__ g,
               const float* __restrict__ b, u16* __restrict__ out)
{
    const int row = blockIdx.x;
    const int t = threadIdx.x;
    const float4 v = ((const float4*)(x + (size_t)row*1024))[t];
    float s = v.x + v.y + v.z + v.w;
    float ss = v.x*v.x + v.y*v.y + v.z*v.z + v.w*v.w;
    #pragma unroll
    for (int m = 1; m < 64; m <<= 1) {
        s  += __shfl_xor(s, m);
        ss += __shfl_xor(ss, m);
    }
    __shared__ float red[8];
    const int wave = t >> 6;
    if ((t & 63) == 0) { red[wave] = s; red[4 + wave] = ss; }
    __syncthreads();
    s  = red[0] + red[1] + red[2] + red[3];
    ss = red[4] + red[5] + red[6] + red[7];
    const float mu = s * (1.f/1024.f);
    const float rs = rsqrtf(ss * (1.f/1024.f) - mu*mu + 1e-5f);
    const float4 gv = ((const float4*)g)[t];
    const float4 bv = ((const float4*)b)[t];
    ushort4 ov;
    ov.x = f2bf((v.x - mu)*rs*gv.x + bv.x);
    ov.y = f2bf((v.y - mu)*rs*gv.y + bv.y);
    ov.z = f2bf((v.z - mu)*rs*gv.z + bv.z);
    ov.w = f2bf((v.w - mu)*rs*gv.w + bv.w);
    ((ushort4*)(out + (size_t)row*1024))[t] = ov;
}

// ---------------------------------------------------------------- GEMM 256xBN, BK=64, counted-vmcnt 4-phase
// A [8192][K] bf16 rm, BT [N][K] bf16 rm. 512 threads = 8 waves (2M x 4N).
// Halves: A-half QM = rows QM*128..QM*128+127 (chunks 2QM,2QM+1);
//         B-half QN = cols QN*(BN/2)..        (chunks QN*NCB/2..).
// Staging spread: P0 issues A0'+B0', P1 issues B1', P2 issues A1'.
// Steady waits (BN=256): P0-end vmcnt(6)->B1 ready; P1-end vmcnt(6)->A1; P3-end vmcnt(4)->A0',B0'.
template<int NWG, int BN, int N, int K, int EPI>
__global__ __launch_bounds__(512, 2)
void gemm256_kernel(const u16* __restrict__ A, const u16* __restrict__ BT,
                    float* __restrict__ out_f32, u16* __restrict__ out_bf16,
                    const float* __restrict__ bias, const float* __restrict__ res,
                    u16* __restrict__ qbuf, u16* __restrict__ kbuf, u16* __restrict__ vt)
{
    constexpr int NI  = BN / 128;      // B-frags per phase (2 for BN=256, 1 for BN=128)
    constexpr int NCB = BN / 64;       // B staging chunks
    __shared__ u16 As[2][256*64];
    __shared__ u16 Bs[2][BN*64];

    const int bid = blockIdx.x;
    const int tid = ((bid & 7) * (NWG / 8)) + (bid >> 3);   // bijective XCD swizzle
    const int m0 = (tid & 31) * 256;
    const int n0 = (tid >> 5) * BN;
    const int t = threadIdx.x;
    const int lane = t & 63;
    const int l15 = lane & 15, lg = lane >> 4;
    const int wid = t >> 6;
    const int wm = wid >> 2, wn = wid & 3;
    const int swzf = (l15 & 7) << 4;

    f32x4 acc[2][2][4][NI] = {};
    bf16x8 af[4][2], b0[NI][2], b1[NI][2];

    const int srow = t >> 3;
    const int sg8  = ((t & 7) ^ (srow & 7)) * 8;   // pre-swizzled src col (u16)

#define SA_H(BUF, K0, H) do { \
    _Pragma("unroll") \
    for (int i = 2*(H); i < 2*(H)+2; ++i) \
        gload_lds16(A + (size_t)(m0 + i*64 + srow)*K + (K0) + sg8, &As[BUF][i*4096 + t*8]); \
} while (0)
#define SB_H(BUF, K0, H) do { \
    _Pragma("unroll") \
    for (int i = (NCB/2)*(H); i < (NCB/2)*(H) + NCB/2; ++i) \
        gload_lds16(BT + (size_t)(n0 + i*64 + srow)*K + (K0) + sg8, &Bs[BUF][i*4096 + t*8]); \
} while (0)
#define RD_A(CUR, QM) do { \
    _Pragma("unroll") \
    for (int mi = 0; mi < 4; ++mi) \
        _Pragma("unroll") \
        for (int kk = 0; kk < 2; ++kk) \
            af[mi][kk] = *(const bf16x8*)((const char*)&As[CUR][0] \
                + ((QM)*128 + wm*64 + mi*16 + l15)*128 + ((kk*64 + lg*16) ^ swzf)); \
} while (0)
#define RD_B(CUR, QN, DST) do { \
    _Pragma("unroll") \
    for (int ni = 0; ni < NI; ++ni) \
        _Pragma("unroll") \
        for (int kk = 0; kk < 2; ++kk) \
            DST[ni][kk] = *(const bf16x8*)((const char*)&Bs[CUR][0] \
                + ((QN)*(BN/2) + wn*(BN/8) + ni*16 + l15)*128 + ((kk*64 + lg*16) ^ swzf)); \
} while (0)
#define MFMAQ(QM, QN, BF) do { \
    _Pragma("unroll") \
    for (int mi = 0; mi < 4; ++mi) \
        _Pragma("unroll") \
        for (int ni = 0; ni < NI; ++ni) \
            _Pragma("unroll") \
            for (int kk = 0; kk < 2; ++kk) \
                acc[QM][QN][mi][ni] = __builtin_amdgcn_mfma_f32_16x16x32_bf16( \
                    af[mi][kk], BF[ni][kk], acc[QM][QN][mi][ni], 0, 0, 0); \
} while (0)
#define PH_MFMA(QM, QN, BF) do { \
    __builtin_amdgcn_sched_barrier(0); \
    __builtin_amdgcn_s_barrier(); \
    asm volatile("s_waitcnt lgkmcnt(0)" ::: "memory"); \
    __builtin_amdgcn_sched_barrier(0); \
    __builtin_amdgcn_s_setprio(1); \
    MFMAQ(QM, QN, BF); \
    __builtin_amdgcn_s_setprio(0); \
    __builtin_amdgcn_sched_barrier(0); \
} while (0)
#define BAR __builtin_amdgcn_s_barrier()
#define W_B1S do { if constexpr (BN == 256) asm volatile("s_waitcnt vmcnt(6)":::"memory"); \
                   else                     asm volatile("s_waitcnt vmcnt(5)":::"memory"); } while (0)
#define W_A1S do { if constexpr (BN == 256) asm volatile("s_waitcnt vmcnt(6)":::"memory"); \
                   else                     asm volatile("s_waitcnt vmcnt(4)":::"memory"); } while (0)
#define W_01S do { if constexpr (BN == 256) asm volatile("s_waitcnt vmcnt(4)":::"memory"); \
                   else                     asm volatile("s_waitcnt vmcnt(3)":::"memory"); } while (0)
#define W_B1L asm volatile("s_waitcnt vmcnt(2)":::"memory")
#define W_A1L asm volatile("s_waitcnt vmcnt(0)":::"memory")

    // prologue: stage tile 0 in steady-state issue order (A0,B0 | B1 | A1)
    SA_H(0, 0, 0); SB_H(0, 0, 0);
    SB_H(0, 0, 1);
    SA_H(0, 0, 1);
    W_01S; BAR;

    const int NKT = K / 64;
    for (int kt = 0; kt < NKT - 1; ++kt) {
        const int cur = kt & 1, nxt = cur ^ 1;
        const int k1 = (kt + 1) * 64;
        // P0: quad (0,0); issue next A0,B0
        RD_A(cur, 0); RD_B(cur, 0, b0);
        SA_H(nxt, k1, 0); SB_H(nxt, k1, 0);
        PH_MFMA(0, 0, b0);
        W_B1S; BAR;
        // P1: quad (0,1); issue next B1
        RD_B(cur, 1, b1);
        SB_H(nxt, k1, 1);
        PH_MFMA(0, 1, b1);
        W_A1S; BAR;
        // P2: quad (1,1); issue next A1
        RD_A(cur, 1);
        SA_H(nxt, k1, 1);
        PH_MFMA(1, 1, b1);
        BAR;
        // P3: quad (1,0) — regs only
        PH_MFMA(1, 0, b0);
        W_01S; BAR;
    }
    {   // peeled last iteration: drain 2 -> 0
        const int cur = (NKT - 1) & 1;
        RD_A(cur, 0); RD_B(cur, 0, b0);
        PH_MFMA(0, 0, b0);
        W_B1L; BAR;
        RD_B(cur, 1, b1);
        PH_MFMA(0, 1, b1);
        W_A1L; BAR;
        RD_A(cur, 1);
        PH_MFMA(1, 1, b1);
        BAR;
        PH_MFMA(1, 0, b0);
    }
#undef SA_H
#undef SB_H
#undef RD_A
#undef RD_B
#undef MFMAQ
#undef PH_MFMA
#undef BAR
#undef W_B1S
#undef W_A1S
#undef W_01S
#undef W_B1L
#undef W_A1L

    // ---- epilogue
    #pragma unroll
    for (int qm = 0; qm < 2; ++qm)
      #pragma unroll
      for (int qn = 0; qn < 2; ++qn)
        #pragma unroll
        for (int mi = 0; mi < 4; ++mi)
          #pragma unroll
          for (int ni = 0; ni < NI; ++ni) {
            const int gc = n0 + qn*(BN/2) + wn*(BN/8) + ni*16 + l15;
            #pragma unroll
            for (int j = 0; j < 4; ++j) {
                const int gr = m0 + qm*128 + wm*64 + mi*16 + lg*4 + j;
                float v = acc[qm][qn][mi][ni][j];
                if constexpr (EPI == 0) {
                    u16 bv = f2bf(v);
                    if (gc < 1024) {
                        qbuf[(size_t)gr*1024 + gc] = bv;
                    } else if (gc < 2048) {
                        kbuf[(size_t)gr*1024 + (gc - 1024)] = bv;
                    } else {
                        const int hd = gc - 2048;
                        const int bb = gr >> 11, tt = gr & 2047;
                        vt[(size_t)((bb*16 + (hd >> 6))*64 + (hd & 63))*2048 + tt] = bv;
                    }
                } else if constexpr (EPI == 1) {
                    out_f32[(size_t)gr*N + gc] = v + bias[gc] + res[(size_t)gr*N + gc];
                } else {
                    out_bf16[(size_t)gr*N + gc] = f2bf(fmaxf(v + bias[gc], 0.f));
                }
            }
          }
}

// ---------------------------------------------------------------- flash attention v3 (unchanged)
__device__ __forceinline__ void attn_qtile(
    bf16x8 (&qf)[2][2], f32x4 (&o)[2][4], float (&mprev)[2][4], float (&lsum)[2][4],
    const u16* Ksc, const u16* Vsc, u16* pl,
    int key0, int q0, int l15, int lg, int swzf, int swzp)
{
    #pragma unroll
    for (int mi = 0; mi < 2; ++mi) {
        if (key0 > q0 + mi*16 + 15) continue;
        f32x4 s[4] = {};
        #pragma unroll
        for (int n = 0; n < 4; ++n)
            #pragma unroll
            for (int kk = 0; kk < 2; ++kk) {
                const int row = n*16 + l15;
                bf16x8 kf = *(const bf16x8*)((const char*)Ksc
                                + row*128 + ((kk*64 + lg*16) ^ swzf));
                s[n] = __builtin_amdgcn_mfma_f32_16x16x32_bf16(qf[mi][kk], kf, s[n], 0, 0, 0);
            }
        const bool domask = (key0 + 63) > (q0 + mi*16);
        float tm[4] = {-INFINITY, -INFINITY, -INFINITY, -INFINITY};
        #pragma unroll
        for (int n = 0; n < 4; ++n)
            #pragma unroll
            for (int j = 0; j < 4; ++j) {
                float sv = s[n][j] * 0.03125f;
                if (domask && (key0 + n*16 + l15 > q0 + mi*16 + lg*4 + j)) sv = -INFINITY;
                s[n][j] = sv;
                tm[j] = fmaxf(tm[j], sv);
            }
        #pragma unroll
        for (int m = 1; m < 16; m <<= 1)
            #pragma unroll
            for (int j = 0; j < 4; ++j)
                tm[j] = fmaxf(tm[j], __shfl_xor(tm[j], m, 16));
        float alpha[4], rsum[4];
        #pragma unroll
        for (int j = 0; j < 4; ++j) {
            float mn = fmaxf(mprev[mi][j], tm[j]);
            alpha[j] = __expf(mprev[mi][j] - mn);
            mprev[mi][j] = mn;
            rsum[j] = 0.f;
        }
        #pragma unroll
        for (int n = 0; n < 4; ++n)
            #pragma unroll
            for (int j = 0; j < 4; ++j) {
                float pv = __expf(s[n][j] - mprev[mi][j]);
                rsum[j] += pv;
                const int qq = lg*4 + j;
                pl[qq*64 + ((n*16 + l15) ^ ((qq & 7) * 8))] = f2bf(pv);
            }
        #pragma unroll
        for (int m = 1; m < 16; m <<= 1)
            #pragma unroll
            for (int j = 0; j < 4; ++j)
                rsum[j] += __shfl_xor(rsum[j], m, 16);
        #pragma unroll
        for (int j = 0; j < 4; ++j)
            lsum[mi][j] = lsum[mi][j]*alpha[j] + rsum[j];
        #pragma unroll
        for (int dn = 0; dn < 4; ++dn)
            #pragma unroll
            for (int j = 0; j < 4; ++j)
                o[mi][dn][j] *= alpha[j];
        bf16x8 pf[2];
        #pragma unroll
        for (int kk = 0; kk < 2; ++kk)
            pf[kk] = *(const bf16x8*)(pl + l15*64 + ((kk*32 + lg*8) ^ swzp));
        #pragma unroll
        for (int dn = 0; dn < 4; ++dn)
            #pragma unroll
            for (int kk = 0; kk < 2; ++kk) {
                const int row = dn*16 + l15;
                bf16x8 vf = *(const bf16x8*)((const char*)Vsc
                                + row*128 + ((kk*64 + lg*16) ^ swzf));
                o[mi][dn] = __builtin_amdgcn_mfma_f32_16x16x32_bf16(pf[kk], vf, o[mi][dn], 0, 0, 0);
            }
    }
}

__global__ __launch_bounds__(256, 2)
void attn_kernel(const u16* __restrict__ q, const u16* __restrict__ k,
                 const u16* __restrict__ vt, u16* __restrict__ out)
{
    __shared__ u16 Ks[2][4096];
    __shared__ u16 Vs[2][4096];
    __shared__ u16 Plds[4][1024];

    const int bh = blockIdx.x & 63;
    const int pair = blockIdx.x >> 6;
    const int b = bh >> 4, h = bh & 15;
    const int wave = threadIdx.x >> 6, lane = threadIdx.x & 63;
    const int l15 = lane & 15, lg = lane >> 4;
    const int qA = pair, qB = 15 - pair;
    const int q0A = qA*128 + wave*32;
    const int q0B = qB*128 + wave*32;
    const u16* Qp = q + (size_t)b*2048*1024 + h*64;
    const u16* Kp = k + (size_t)b*2048*1024 + h*64;
    const u16* Vp = vt + (size_t)bh*64*2048;
    u16* pl = Plds[wave];

    bf16x8 qfA[2][2], qfB[2][2];
    #pragma unroll
    for (int mi = 0; mi < 2; ++mi)
        #pragma unroll
        for (int kk = 0; kk < 2; ++kk) {
            qfA[mi][kk] = *(const bf16x8*)(Qp + (size_t)(q0A + mi*16 + l15)*1024 + kk*32 + lg*8);
            qfB[mi][kk] = *(const bf16x8*)(Qp + (size_t)(q0B + mi*16 + l15)*1024 + kk*32 + lg*8);
        }

    const int srow0 = wave*8 + (lane >> 3);
    const int scol  = ((lane & 7) ^ (srow0 & 7)) << 3;
    const int swzf  = (l15 & 7) << 4;
    const int swzp  = (l15 & 7) << 3;

    f32x4 oA[2][4] = {}, oB[2][4] = {};
    float mprevA[2][4], lsumA[2][4], mprevB[2][4], lsumB[2][4];
    #pragma unroll
    for (int mi = 0; mi < 2; ++mi)
        #pragma unroll
        for (int j = 0; j < 4; ++j) {
            mprevA[mi][j] = -INFINITY; lsumA[mi][j] = 0.f;
            mprevB[mi][j] = -INFINITY; lsumB[mi][j] = 0.f;
        }

    const int nkt = 32 - 2*pair;

    #define STAGE(buf, key0_) do { \
        gload_lds16(Kp + (size_t)((key0_) + srow0)*1024 + scol,      &Ks[buf][wave*512]); \
        gload_lds16(Kp + (size_t)((key0_) + srow0 + 32)*1024 + scol, &Ks[buf][(4+wave)*512]); \
        gload_lds16(Vp + (size_t)srow0*2048 + (key0_) + scol,        &Vs[buf][wave*512]); \
        gload_lds16(Vp + (size_t)(srow0+32)*2048 + (key0_) + scol,   &Vs[buf][(4+wave)*512]); \
    } while (0)

    STAGE(0, 0);

    for (int kt = 0; kt < nkt; ++kt) {
        const int cur = kt & 1;
        const int key0 = kt * 64;
        if (kt + 1 < nkt) {
            STAGE(cur ^ 1, key0 + 64);
            asm volatile("s_waitcnt vmcnt(4)" ::: "memory");
        } else {
            asm volatile("s_waitcnt vmcnt(0)" ::: "memory");
        }
        __builtin_amdgcn_s_barrier();
        __builtin_amdgcn_sched_barrier(0);

        if (key0 <= q0A + 31)
            attn_qtile(qfA, oA, mprevA, lsumA, &Ks[cur][0], &Vs[cur][0], pl,
                       key0, q0A, l15, lg, swzf, swzp);
        if (key0 <= q0B + 31)
            attn_qtile(qfB, oB, mprevB, lsumB, &Ks[cur][0], &Vs[cur][0], pl,
                       key0, q0B, l15, lg, swzf, swzp);

        __builtin_amdgcn_sched_barrier(0);
        __builtin_amdgcn_s_barrier();
    }
    #undef STAGE

    #pragma unroll
    for (int mi = 0; mi < 2; ++mi)
        #pragma unroll
        for (int dn = 0; dn < 4; ++dn)
            #pragma unroll
            for (int j = 0; j < 4; ++j) {
                float vA = oA[mi][dn][j] / lsumA[mi][j];
                out[(size_t)(b*2048 + q0A + mi*16 + lg*4 + j)*1024 + h*64 + dn*16 + l15] = f2bf(vA);
                float vB = oB[mi][dn][j] / lsumB[mi][j];
                out[(size_t)(b*2048 + q0B + mi*16 + lg*4 + j)*1024 + h*64 + dn*16 + l15] = f2bf(vB);
            }
}

// ---------------------------------------------------------------- launch
#define MB(x) ((size_t)(x) << 20)

extern "C" void kernel_launch(void* const* d_in, const int* in_sizes, int n_in,
                              void* d_out, int out_size, void* d_ws, size_t ws_size,
                              hipStream_t stream) {
    const float* x      = (const float*)d_in[0];
    const float* Wq     = (const float*)d_in[1];
    const float* Wk     = (const float*)d_in[2];
    const float* Wv     = (const float*)d_in[3];
    const float* Wproj  = (const float*)d_in[4];
    const float* bproj  = (const float*)d_in[5];
    const float* ln1_g  = (const float*)d_in[6];
    const float* ln1_b  = (const float*)d_in[7];
    const float* ln2_g  = (const float*)d_in[8];
    const float* ln2_b  = (const float*)d_in[9];
    const float* W1     = (const float*)d_in[10];
    const float* b1     = (const float*)d_in[11];
    const float* W2     = (const float*)d_in[12];
    const float* b2     = (const float*)d_in[13];
    float* out = (float*)d_out;

    char* ws = (char*)d_ws;
    u16*  h      = (u16*)(ws + MB(0));
    u16*  qbuf   = (u16*)(ws + MB(16));
    u16*  kbuf   = (u16*)(ws + MB(32));
    u16*  vt     = (u16*)(ws + MB(48));
    u16*  attn   = (u16*)(ws + MB(64));
    float* x2    = (float*)(ws + MB(80));
    u16*  BTqkv  = (u16*)(ws + MB(112));
    u16*  BTproj = (u16*)(ws + MB(118));
    u16*  BT1    = (u16*)(ws + MB(120));
    u16*  BT2    = (u16*)(ws + MB(128));
    u16*  ff     = (u16*)(ws + MB(16));
    u16*  h2     = h;

    transpose_cvt<<<dim3(1,16,16),  256, 0, stream>>>(Wq,    BTqkv,             1024, 64);
    transpose_cvt<<<dim3(1,16,16),  256, 0, stream>>>(Wk,    BTqkv + (1<<20),   1024, 64);
    transpose_cvt<<<dim3(1,16,16),  256, 0, stream>>>(Wv,    BTqkv + (2<<20),   1024, 64);
    transpose_cvt<<<dim3(16,16,1),  256, 0, stream>>>(Wproj, BTproj,            1024, 1024);
    transpose_cvt<<<dim3(64,16,1),  256, 0, stream>>>(W1,    BT1,               1024, 4096);
    transpose_cvt<<<dim3(16,64,1),  256, 0, stream>>>(W2,    BT2,               4096, 1024);

    ln_kernel<<<8192, 256, 0, stream>>>(x, ln1_g, ln1_b, h);
    gemm256_kernel<384,256,3072,1024,0><<<384, 512, 0, stream>>>(h, BTqkv, nullptr, nullptr,
        nullptr, nullptr, qbuf, kbuf, vt);
    attn_kernel<<<512, 256, 0, stream>>>(qbuf, kbuf, vt, attn);
    gemm256_kernel<256,128,1024,1024,1><<<256, 512, 0, stream>>>(attn, BTproj, x2, nullptr,
        bproj, x, nullptr, nullptr, nullptr);
    ln_kernel<<<8192, 256, 0, stream>>>(x2, ln2_g, ln2_b, h2);
    gemm256_kernel<512,256,4096,1024,2><<<512, 512, 0, stream>>>(h2, BT1, nullptr, ff,
        b1, nullptr, nullptr, nullptr, nullptr);
    gemm256_kernel<256,128,1024,4096,1><<<256, 512, 0, stream>>>(ff, BT2, out, nullptr,
        b2, x2, nullptr, nullptr, nullptr);
}